// Round 1
// baseline (4101.719 us; speedup 1.0000x reference)
//
#include <hip/hip_runtime.h>
#include <hip/hip_bf16.h>

// Problem constants
constexpr int Bq  = 16;
constexpr int Lq  = 24;
constexpr int Tq  = 400;
constexpr int Dq  = 1024;
constexpr int Eq  = 512;
constexpr int RIN = Eq * Lq;   // 12288
constexpr int RH  = 128;
constexpr float TEMPER = 1.75f;
constexpr float ALPHA  = 0.325f;

constexpr int RSPLIT = 8;
constexpr int RCOLS  = RH + Lq;   // 152

// ---------------------------------------------------------------------------
// Batched SGEMM: C[bl] = act(A[bl] @ Bw[l] + bias[l]) ; A [T x K] row-major,
// Bw [K x 512] row-major, C [T x 512]. Tile 64x256, 256 thr, 8x8 micro.
// ---------------------------------------------------------------------------
__global__ __launch_bounds__(256) void gemm_bias_act(
    const float* __restrict__ A, const float* __restrict__ Bw,
    const float* __restrict__ bias, float* __restrict__ C,
    const int K, const int lda,
    const long aStride, const long bStride, const int doRelu)
{
    constexpr int BM = 64, BN = 256, KT = 16;
    constexpr int PA = 68, PB = 260;           // pad: <=2-way LDS conflicts
    __shared__ float As[KT][PA];
    __shared__ float Bs[KT][PB];

    const int tid   = threadIdx.x;
    const int l     = blockIdx.y;
    const int b     = blockIdx.z;
    const int tileM = blockIdx.x >> 1;          // 0..6
    const int n0    = (blockIdx.x & 1) * BN;    // 0 or 256
    const int row0  = tileM * BM;

    const float* Ab    = A + (long)(b * Lq + l) * aStride;
    const float* Bb    = Bw + (long)l * bStride + n0;
    const float* biasb = bias + l * Eq + n0;
    float*       Cb    = C + (long)(b * Lq + l) * ((long)Tq * Eq) + n0;

    // wave-local 8x8 lane layout -> conflict-free-ish fragment reads
    const int lane = tid & 63, wave = tid >> 6;
    const int ty = lane >> 3;                   // 0..7   (rows)
    const int tx = (lane & 7) + (wave << 3);    // 0..31  (cols)

    // staging indices
    const int arow = tid >> 2;                  // 0..63
    const int akq  = (tid & 3) * 4;             // 0,4,8,12
    const int brow = tid >> 4;                  // 0..15
    const int bcol = (tid & 15) * 16;           // 0..240

    const int  growA  = row0 + arow;
    const bool aValid = growA < Tq;

    float acc[8][8];
    #pragma unroll
    for (int i = 0; i < 8; ++i)
        #pragma unroll
        for (int j = 0; j < 8; ++j) acc[i][j] = 0.f;

    for (int k0 = 0; k0 < K; k0 += KT) {
        float4 av = make_float4(0.f, 0.f, 0.f, 0.f);
        if (aValid) av = *(const float4*)(Ab + (long)growA * lda + k0 + akq);
        As[akq + 0][arow] = av.x;
        As[akq + 1][arow] = av.y;
        As[akq + 2][arow] = av.z;
        As[akq + 3][arow] = av.w;

        const float* bp = Bb + (long)(k0 + brow) * Eq + bcol;
        float4 b0 = *(const float4*)(bp + 0);
        float4 b1 = *(const float4*)(bp + 4);
        float4 b2 = *(const float4*)(bp + 8);
        float4 b3 = *(const float4*)(bp + 12);
        *(float4*)&Bs[brow][bcol + 0]  = b0;
        *(float4*)&Bs[brow][bcol + 4]  = b1;
        *(float4*)&Bs[brow][bcol + 8]  = b2;
        *(float4*)&Bs[brow][bcol + 12] = b3;

        __syncthreads();

        #pragma unroll
        for (int kk = 0; kk < KT; ++kk) {
            float af[8], bf[8];
            *(float4*)&af[0] = *(const float4*)&As[kk][ty * 8];
            *(float4*)&af[4] = *(const float4*)&As[kk][ty * 8 + 4];
            *(float4*)&bf[0] = *(const float4*)&Bs[kk][tx * 8];
            *(float4*)&bf[4] = *(const float4*)&Bs[kk][tx * 8 + 4];
            #pragma unroll
            for (int i = 0; i < 8; ++i)
                #pragma unroll
                for (int j = 0; j < 8; ++j)
                    acc[i][j] = fmaf(af[i], bf[j], acc[i][j]);
        }
        __syncthreads();
    }

    float bv[8];
    *(float4*)&bv[0] = *(const float4*)(biasb + tx * 8);
    *(float4*)&bv[4] = *(const float4*)(biasb + tx * 8 + 4);

    #pragma unroll
    for (int i = 0; i < 8; ++i) {
        const int gr = row0 + ty * 8 + i;
        if (gr < Tq) {
            float outv[8];
            #pragma unroll
            for (int j = 0; j < 8; ++j) {
                float v = acc[i][j] + bv[j];
                if (doRelu) v = fmaxf(v, 0.f);
                outv[j] = v;
            }
            *(float4*)(Cb + (long)gr * Eq + tx * 8)     = *(float4*)&outv[0];
            *(float4*)(Cb + (long)gr * Eq + tx * 8 + 4) = *(float4*)&outv[4];
        }
    }
}

// ---------------------------------------------------------------------------
// Per-(b,l): score = x2 . wa + ba ; softmax over T ; pooled = sum_t w_t x2[t]
// ---------------------------------------------------------------------------
__global__ __launch_bounds__(256) void softmax_pool(
    const float* __restrict__ x2, const float* __restrict__ wa,
    const float* __restrict__ ba, float* __restrict__ pooled)
{
    __shared__ float sc[Tq];
    __shared__ float wa_s[Eq];
    __shared__ float red[4];

    const int tid = threadIdx.x;
    const int l = blockIdx.x, b = blockIdx.y;
    const float* xb = x2 + (long)(b * Lq + l) * ((long)Tq * Eq);

    for (int e = tid; e < Eq; e += 256) wa_s[e] = wa[e];
    __syncthreads();

    const int lane = tid & 63, wave = tid >> 6;
    float wf[8];
    #pragma unroll
    for (int q = 0; q < 8; ++q) wf[q] = wa_s[lane * 8 + q];
    const float ba0 = ba[0];

    // scores: one wave per row
    for (int t = wave; t < Tq; t += 4) {
        const float* row = xb + (long)t * Eq + lane * 8;
        float4 v0 = *(const float4*)row;
        float4 v1 = *(const float4*)(row + 4);
        float s = v0.x * wf[0] + v0.y * wf[1] + v0.z * wf[2] + v0.w * wf[3]
                + v1.x * wf[4] + v1.y * wf[5] + v1.z * wf[6] + v1.w * wf[7];
        #pragma unroll
        for (int off = 32; off; off >>= 1) s += __shfl_down(s, off);
        if (lane == 0) sc[t] = s + ba0;
    }
    __syncthreads();

    // block max
    float m = -3.4e38f;
    for (int t = tid; t < Tq; t += 256) m = fmaxf(m, sc[t]);
    #pragma unroll
    for (int off = 32; off; off >>= 1) m = fmaxf(m, __shfl_down(m, off));
    if (lane == 0) red[wave] = m;
    __syncthreads();
    m = fmaxf(fmaxf(red[0], red[1]), fmaxf(red[2], red[3]));
    __syncthreads();

    // exp + sum
    float ssum = 0.f;
    for (int t = tid; t < Tq; t += 256) {
        float e = expf(sc[t] - m);
        sc[t] = e;
        ssum += e;
    }
    #pragma unroll
    for (int off = 32; off; off >>= 1) ssum += __shfl_down(ssum, off);
    if (lane == 0) red[wave] = ssum;
    __syncthreads();
    const float inv = 1.f / (red[0] + red[1] + red[2] + red[3]);
    __syncthreads();
    for (int t = tid; t < Tq; t += 256) sc[t] *= inv;
    __syncthreads();

    // pooled
    float* pout = pooled + (long)(b * Lq + l) * Eq;
    for (int e = tid; e < Eq; e += 256) {
        float a0 = 0.f;
        #pragma unroll 4
        for (int t = 0; t < Tq; ++t) a0 = fmaf(sc[t], xb[(long)t * Eq + e], a0);
        pout[e] = a0;
    }
}

// ---------------------------------------------------------------------------
// Router split-K partials: part[b][s][j] = sum_{i in chunk} ri[i] * W[i][j]
// j<128 -> Wr1 column ; j in [128,152) -> Wn column
// ---------------------------------------------------------------------------
__global__ __launch_bounds__(192) void router_partial(
    const float* __restrict__ pooled, const float* __restrict__ Wr1,
    const float* __restrict__ Wn, float* __restrict__ part)
{
    constexpr int CH = RIN / RSPLIT;   // 1536
    __shared__ float ri_s[CH];

    const int b = blockIdx.x, s = blockIdx.y, j = threadIdx.x;
    const int i0 = s * CH;
    const float* rib = pooled + (long)b * RIN + i0;

    for (int i = j; i < CH; i += 192) ri_s[i] = rib[i];
    __syncthreads();

    float acc = 0.f;
    if (j < RH) {
        const float* w = Wr1 + (long)i0 * RH + j;
        #pragma unroll 8
        for (int i = 0; i < CH; ++i) acc = fmaf(ri_s[i], w[(long)i * RH], acc);
    } else if (j < RCOLS) {
        const int jn = j - RH;
        const float* w = Wn + (long)i0 * Lq + jn;
        #pragma unroll 8
        for (int i = 0; i < CH; ++i) acc = fmaf(ri_s[i], w[(long)i * Lq], acc);
    }
    if (j < RCOLS) part[((long)b * RSPLIT + s) * RCOLS + j] = acc;
}

// ---------------------------------------------------------------------------
// Router finish: rh = relu(.) ; ns = softplus(.) ; routing weights
// ---------------------------------------------------------------------------
__global__ __launch_bounds__(64) void router_finish(
    const float* __restrict__ part, const float* __restrict__ noise,
    const float* __restrict__ br1, const float* __restrict__ Wr2,
    const float* __restrict__ br2, const float* __restrict__ bn,
    float* __restrict__ rw_out)
{
    __shared__ float rh[RH];
    __shared__ float ns[Lq];
    const int b = blockIdx.x, tid = threadIdx.x;

    for (int j = tid; j < RCOLS; j += 64) {
        float acc = 0.f;
        #pragma unroll
        for (int s = 0; s < RSPLIT; ++s)
            acc += part[((long)b * RSPLIT + s) * RCOLS + j];
        if (j < RH) {
            rh[j] = fmaxf(acc + br1[j], 0.f);
        } else {
            float v = acc + bn[j - RH];
            ns[j - RH] = (v > 20.f) ? v : log1pf(expf(v));
        }
    }
    __syncthreads();

    if (tid < Lq) {
        float acc = br2[tid];
        #pragma unroll 8
        for (int i = 0; i < RH; ++i) acc = fmaf(rh[i], Wr2[i * Lq + tid], acc);
        float z = (acc + noise[b * Lq + tid] * ns[tid]) * (1.f / TEMPER);
        float learned = 1.f / (1.f + expf(-z));
        rw_out[b * Lq + tid] = ALPHA * learned + (1.f - ALPHA) / (float)Lq;
    }
}

// ---------------------------------------------------------------------------
// fused = sum_l pooled*rw ; LayerNorm ; classifier
// ---------------------------------------------------------------------------
__device__ __forceinline__ float blockSum256(float v, volatile float* red)
{
    const int lane = threadIdx.x & 63, wave = threadIdx.x >> 6;
    #pragma unroll
    for (int off = 32; off; off >>= 1) v += __shfl_down(v, off);
    __syncthreads();
    if (lane == 0) red[wave] = v;
    __syncthreads();
    return red[0] + red[1] + red[2] + red[3];
}

__global__ __launch_bounds__(256) void fuse_classify(
    const float* __restrict__ pooled, const float* __restrict__ rw,
    const float* __restrict__ ln_g, const float* __restrict__ ln_b,
    const float* __restrict__ Wc1, const float* __restrict__ bc1,
    const float* __restrict__ Wc2, const float* __restrict__ bc2,
    float* __restrict__ fusedn_out, float* __restrict__ logits_out)
{
    __shared__ float rw_s[Lq];
    __shared__ float fn[Eq];
    __shared__ float red[4];

    const int b = blockIdx.x, tid = threadIdx.x;
    if (tid < Lq) rw_s[tid] = rw[b * Lq + tid];
    __syncthreads();

    const float* pb = pooled + (long)b * RIN;
    float f0 = 0.f, f1 = 0.f;
    #pragma unroll
    for (int l = 0; l < Lq; ++l) {
        f0 = fmaf(pb[l * Eq + tid],       rw_s[l], f0);
        f1 = fmaf(pb[l * Eq + tid + 256], rw_s[l], f1);
    }

    const float mean = blockSum256(f0 + f1, red) * (1.f / Eq);
    const float d0 = f0 - mean, d1 = f1 - mean;
    const float var = blockSum256(d0 * d0 + d1 * d1, red) * (1.f / Eq);
    const float rstd = rsqrtf(var + 1e-5f);

    const float n0v = d0 * rstd * ln_g[tid]       + ln_b[tid];
    const float n1v = d1 * rstd * ln_g[tid + 256] + ln_b[tid + 256];
    fn[tid] = n0v;
    fn[tid + 256] = n1v;
    fusedn_out[(long)b * Eq + tid]       = n0v;
    fusedn_out[(long)b * Eq + tid + 256] = n1v;
    __syncthreads();

    float acc = bc1[tid];
    #pragma unroll 8
    for (int f = 0; f < Eq; ++f) acc = fmaf(fn[f], Wc1[(long)f * 256 + tid], acc);
    const float c = fmaxf(acc, 0.f);

    const float t0 = blockSum256(c * Wc2[tid * 2 + 0], red);
    const float t1 = blockSum256(c * Wc2[tid * 2 + 1], red);
    if (tid == 0) {
        logits_out[b * 2 + 0] = t0 + bc2[0];
        logits_out[b * 2 + 1] = t1 + bc2[1];
    }
}

// ---------------------------------------------------------------------------
extern "C" void kernel_launch(void* const* d_in, const int* in_sizes, int n_in,
                              void* d_out, int out_size, void* d_ws, size_t ws_size,
                              hipStream_t stream)
{
    const float* h     = (const float*)d_in[0];
    const float* noise = (const float*)d_in[1];
    const float* We1   = (const float*)d_in[2];
    const float* be1   = (const float*)d_in[3];
    const float* We2   = (const float*)d_in[4];
    const float* be2   = (const float*)d_in[5];
    const float* wa    = (const float*)d_in[6];
    const float* ba    = (const float*)d_in[7];
    const float* Wr1   = (const float*)d_in[8];
    const float* br1   = (const float*)d_in[9];
    const float* Wr2   = (const float*)d_in[10];
    const float* br2   = (const float*)d_in[11];
    const float* Wn    = (const float*)d_in[12];
    const float* bn    = (const float*)d_in[13];
    const float* ln_g  = (const float*)d_in[14];
    const float* ln_b  = (const float*)d_in[15];
    const float* Wc1   = (const float*)d_in[16];
    const float* bc1   = (const float*)d_in[17];
    const float* Wc2   = (const float*)d_in[18];
    const float* bc2   = (const float*)d_in[19];

    float* out = (float*)d_out;
    // output layout: logits[16*2] | rw[16*24] | fused_n[16*512] | pooled[16*24*512]
    float* logits_out = out;
    float* rw_out     = out + 32;
    float* fusedn_out = out + 416;
    float* pooled_out = out + 8608;

    // workspace: x1 (B*L*T*E) | x2 (B*L*T*E) | router partials
    float* x1   = (float*)d_ws;
    float* x2   = x1 + (long)Bq * Lq * Tq * Eq;   // 78,643,200 floats
    float* part = x2 + (long)Bq * Lq * Tq * Eq;

    dim3 gemmGrid(14, Lq, Bq);   // x: 7 M-tiles * 2 N-tiles

    // Stage 1: x1 = relu(h @ We1 + be1)
    gemm_bias_act<<<gemmGrid, 256, 0, stream>>>(
        h, We1, be1, x1, Dq, Dq, (long)Tq * Dq, (long)Dq * Eq, 1);
    // Stage 2: x2 = x1 @ We2 + be2
    gemm_bias_act<<<gemmGrid, 256, 0, stream>>>(
        x1, We2, be2, x2, Eq, Eq, (long)Tq * Eq, (long)Eq * Eq, 0);
    // softmax-pool -> pooled (written straight into d_out)
    softmax_pool<<<dim3(Lq, Bq), 256, 0, stream>>>(x2, wa, ba, pooled_out);
    // router
    router_partial<<<dim3(Bq, RSPLIT), 192, 0, stream>>>(pooled_out, Wr1, Wn, part);
    router_finish<<<Bq, 64, 0, stream>>>(part, noise, br1, Wr2, br2, bn, rw_out);
    // fuse + LN + classifier
    fuse_classify<<<Bq, 256, 0, stream>>>(pooled_out, rw_out, ln_g, ln_b,
                                          Wc1, bc1, Wc2, bc2,
                                          fusedn_out, logits_out);
}

// Round 2
// 1606.330 us; speedup vs baseline: 2.5535x; 2.5535x over previous
//
#include <hip/hip_runtime.h>
#include <hip/hip_bf16.h>

// Problem constants
constexpr int Bq  = 16;
constexpr int Lq  = 24;
constexpr int Tq  = 400;
constexpr int Dq  = 1024;
constexpr int Eq  = 512;
constexpr int RIN = Eq * Lq;   // 12288
constexpr int RH  = 128;
constexpr float TEMPER = 1.75f;
constexpr float ALPHA  = 0.325f;

constexpr int RSPLIT = 8;
constexpr int RCOLS  = RH + Lq;   // 152

typedef _Float16 h8 __attribute__((ext_vector_type(8)));
typedef _Float16 h4 __attribute__((ext_vector_type(4)));
typedef float    f4 __attribute__((ext_vector_type(4)));

__device__ __forceinline__ void gload16(const void* g, void* l) {
    __builtin_amdgcn_global_load_lds(
        (const __attribute__((address_space(1))) unsigned int*)(g),
        (__attribute__((address_space(3))) unsigned int*)(l), 16, 0, 0);
}

// ---------------------------------------------------------------------------
// fp32 -> fp16 elementwise (n4 = count/4)
// ---------------------------------------------------------------------------
__global__ __launch_bounds__(256) void f32_to_f16(
    const float* __restrict__ in, _Float16* __restrict__ out, long n4)
{
    long i = (long)blockIdx.x * 256 + threadIdx.x;
    const long stride = (long)gridDim.x * 256;
    for (; i < n4; i += stride) {
        f4 v = *(const f4*)(in + 4 * i);
        h4 o;
        o[0] = (_Float16)v[0]; o[1] = (_Float16)v[1];
        o[2] = (_Float16)v[2]; o[3] = (_Float16)v[3];
        *(h4*)(out + 4 * i) = o;
    }
}

// ---------------------------------------------------------------------------
// per-l transpose: in [L][R][C] fp32 -> out [L][C][R] fp16
// ---------------------------------------------------------------------------
__global__ __launch_bounds__(256) void transpose_to_f16(
    const float* __restrict__ in, _Float16* __restrict__ out,
    const int R, const int C)
{
    __shared__ float t[32][33];
    const int li = blockIdx.z;
    const int c0 = blockIdx.x * 32, r0 = blockIdx.y * 32;
    const int tx = threadIdx.x & 31, ty = threadIdx.x >> 5;   // 32 x 8
    const float* ip = in + (size_t)li * R * C;
    _Float16*    op = out + (size_t)li * R * C;
    #pragma unroll
    for (int j = 0; j < 4; ++j)
        t[ty + j * 8][tx] = ip[(size_t)(r0 + ty + j * 8) * C + c0 + tx];
    __syncthreads();
    #pragma unroll
    for (int j = 0; j < 4; ++j)
        op[(size_t)(c0 + ty + j * 8) * R + r0 + tx] = (_Float16)t[tx][ty + j * 8];
}

// ---------------------------------------------------------------------------
// fp16 MFMA batched GEMM.
// A: fp16, rows indexed by gm in [0,6400) -> (b = gm/400, t = gm%400),
//    row base ((b*L+li)*T + t)*K, K contiguous.
// Wt: fp16 [L][512][K]  (n-major, K contiguous)
// C : fp16 [B][L][T][512], bias fp32 [L][512], optional ReLU.
// Tile 128x128, BK=32, 4 waves x (4x4) 16x16x32 frags. M=6400=50*128 exact.
// ---------------------------------------------------------------------------
__global__ __launch_bounds__(256) void gemm_f16(
    const _Float16* __restrict__ A, const _Float16* __restrict__ Wt,
    const float* __restrict__ bias, _Float16* __restrict__ Cc,
    const int K, const int doRelu)
{
    __shared__ _Float16 lds[8192];    // A: [0,4096) halves, B: [4096,8192)

    const int tid = threadIdx.x, wv = tid >> 6, ln = tid & 63;
    const int nt = blockIdx.x;        // 0..3
    const int mt = blockIdx.y;        // 0..49
    const int li = blockIdx.z;        // 0..23
    const int n0 = nt * 128;

    // ---- staging: 4 gload16 per thread (2 A, 2 B), pre-swizzled source chunk
    const int srow   = ln >> 2;                         // 0..15
    const int schunk = (ln & 3) ^ ((ln >> 3) & 3);      // XOR swizzle (involution)
    const _Float16* aSrc[2];
    const _Float16* bSrc[2];
    _Float16* aDst[2];
    _Float16* bDst[2];
    #pragma unroll
    for (int i = 0; i < 2; ++i) {
        const int q   = wv * 2 + i;                     // 0..7 (1KB chunks)
        const int row = q * 16 + srow;                  // 0..127
        const int gm  = mt * 128 + row;
        const int bb  = gm / 400, tt = gm - bb * 400;
        aSrc[i] = A + ((size_t)(bb * Lq + li) * Tq + tt) * K + schunk * 8;
        aDst[i] = &lds[q * 512];
        bSrc[i] = Wt + ((size_t)li * 512 + n0 + row) * K + schunk * 8;
        bDst[i] = &lds[4096 + q * 512];
    }

    // ---- fragment LDS byte offsets (swizzle-matched)
    const int rlow = ln & 15, g = ln >> 4;
    const int xorc = g ^ ((rlow >> 1) & 3);
    const int wm = wv >> 1, wn = wv & 1;
    const char* ldsb = (const char*)lds;
    int aoff[4], boff[4];
    #pragma unroll
    for (int i = 0; i < 4; ++i) {
        aoff[i] = (wm * 64 + i * 16 + rlow) * 64 + xorc * 16;
        boff[i] = 8192 + (wn * 64 + i * 16 + rlow) * 64 + xorc * 16;
    }

    f4 acc[4][4];
    #pragma unroll
    for (int i = 0; i < 4; ++i)
        #pragma unroll
        for (int j = 0; j < 4; ++j)
            acc[i][j] = (f4)0.f;

    const int nsteps = K >> 5;
    for (int s = 0; s < nsteps; ++s) {
        gload16(aSrc[0], aDst[0]);
        gload16(aSrc[1], aDst[1]);
        gload16(bSrc[0], bDst[0]);
        gload16(bSrc[1], bDst[1]);
        aSrc[0] += 32; aSrc[1] += 32; bSrc[0] += 32; bSrc[1] += 32;
        __syncthreads();                       // drains vmcnt -> LDS valid

        h8 af[4], bf[4];
        #pragma unroll
        for (int i = 0; i < 4; ++i) af[i] = *(const h8*)(ldsb + aoff[i]);
        #pragma unroll
        for (int i = 0; i < 4; ++i) bf[i] = *(const h8*)(ldsb + boff[i]);
        #pragma unroll
        for (int mf = 0; mf < 4; ++mf)
            #pragma unroll
            for (int nf = 0; nf < 4; ++nf)
                // swapped operands: D[n][m] layout -> n lands in-lane (reg dim)
                acc[mf][nf] = __builtin_amdgcn_mfma_f32_16x16x32_f16(
                    bf[nf], af[mf], acc[mf][nf], 0, 0, 0);
        __syncthreads();                       // protect LDS before next stage
    }

    // ---- epilogue: bias (+ReLU), fp16 pack, 8B stores (n in-lane)
    f4 bv[4];
    #pragma unroll
    for (int nf = 0; nf < 4; ++nf)
        bv[nf] = *(const f4*)(bias + li * 512 + n0 + wn * 64 + nf * 16 + g * 4);

    #pragma unroll
    for (int mf = 0; mf < 4; ++mf) {
        const int gm = mt * 128 + wm * 64 + mf * 16 + rlow;
        const int bb = gm / 400, tt = gm - bb * 400;
        _Float16* crow = Cc + ((size_t)(bb * Lq + li) * Tq + tt) * 512
                         + n0 + wn * 64 + g * 4;
        #pragma unroll
        for (int nf = 0; nf < 4; ++nf) {
            f4 v = acc[mf][nf];
            h4 o;
            #pragma unroll
            for (int r = 0; r < 4; ++r) {
                float x = v[r] + bv[nf][r];
                if (doRelu) x = fmaxf(x, 0.f);
                o[r] = (_Float16)x;
            }
            *(h4*)(crow + nf * 16) = o;
        }
    }
}

// ---------------------------------------------------------------------------
// Per-(b,l): score = x2 . wa + ba ; softmax over T ; pooled = sum_t w_t x2[t]
// x2 fp16
// ---------------------------------------------------------------------------
__global__ __launch_bounds__(256) void softmax_pool_f16(
    const _Float16* __restrict__ x2, const float* __restrict__ wa,
    const float* __restrict__ ba, float* __restrict__ pooled)
{
    __shared__ float sc[Tq];
    __shared__ float red[4];
    __shared__ float part[4][Eq];

    const int tid = threadIdx.x, wv = tid >> 6, ln = tid & 63;
    const int li = blockIdx.x, b = blockIdx.y;
    const _Float16* xb = x2 + (size_t)(b * Lq + li) * Tq * Eq;

    float wf[8];
    #pragma unroll
    for (int q = 0; q < 8; ++q) wf[q] = wa[ln * 8 + q];
    const float ba0 = ba[0];

    // scores: one wave per row
    for (int t = wv; t < Tq; t += 4) {
        h8 v = *(const h8*)(xb + (size_t)t * Eq + ln * 8);
        float s = 0.f;
        #pragma unroll
        for (int q = 0; q < 8; ++q) s += (float)v[q] * wf[q];
        #pragma unroll
        for (int off = 32; off; off >>= 1) s += __shfl_down(s, off);
        if (ln == 0) sc[t] = s + ba0;
    }
    __syncthreads();

    // block max
    float m = -3.4e38f;
    for (int t = tid; t < Tq; t += 256) m = fmaxf(m, sc[t]);
    #pragma unroll
    for (int off = 32; off; off >>= 1) m = fmaxf(m, __shfl_down(m, off));
    if (ln == 0) red[wv] = m;
    __syncthreads();
    m = fmaxf(fmaxf(red[0], red[1]), fmaxf(red[2], red[3]));
    __syncthreads();

    // exp + sum
    float ssum = 0.f;
    for (int t = tid; t < Tq; t += 256) {
        float e = expf(sc[t] - m);
        sc[t] = e;
        ssum += e;
    }
    #pragma unroll
    for (int off = 32; off; off >>= 1) ssum += __shfl_down(ssum, off);
    if (ln == 0) red[wv] = ssum;
    __syncthreads();
    const float inv = 1.f / (red[0] + red[1] + red[2] + red[3]);
    __syncthreads();
    for (int t = tid; t < Tq; t += 256) sc[t] *= inv;
    __syncthreads();

    // pooled: lane owns 8 columns, waves split t
    float accp[8];
    #pragma unroll
    for (int q = 0; q < 8; ++q) accp[q] = 0.f;
    for (int t = wv; t < Tq; t += 4) {
        const float w = sc[t];
        h8 v = *(const h8*)(xb + (size_t)t * Eq + ln * 8);
        #pragma unroll
        for (int q = 0; q < 8; ++q) accp[q] = fmaf((float)v[q], w, accp[q]);
    }
    #pragma unroll
    for (int q = 0; q < 8; ++q) part[wv][ln * 8 + q] = accp[q];
    __syncthreads();

    float* po = pooled + (size_t)(b * Lq + li) * Eq;
    for (int e = tid; e < Eq; e += 256)
        po[e] = part[0][e] + part[1][e] + part[2][e] + part[3][e];
}

// ---------------------------------------------------------------------------
// Router split-K partials (unchanged, fp32 pooled input)
// ---------------------------------------------------------------------------
__global__ __launch_bounds__(192) void router_partial(
    const float* __restrict__ pooled, const float* __restrict__ Wr1,
    const float* __restrict__ Wn, float* __restrict__ part)
{
    constexpr int CH = RIN / RSPLIT;   // 1536
    __shared__ float ri_s[CH];

    const int b = blockIdx.x, s = blockIdx.y, j = threadIdx.x;
    const int i0 = s * CH;
    const float* rib = pooled + (long)b * RIN + i0;

    for (int i = j; i < CH; i += 192) ri_s[i] = rib[i];
    __syncthreads();

    float acc = 0.f;
    if (j < RH) {
        const float* w = Wr1 + (long)i0 * RH + j;
        #pragma unroll 8
        for (int i = 0; i < CH; ++i) acc = fmaf(ri_s[i], w[(long)i * RH], acc);
    } else if (j < RCOLS) {
        const int jn = j - RH;
        const float* w = Wn + (long)i0 * Lq + jn;
        #pragma unroll 8
        for (int i = 0; i < CH; ++i) acc = fmaf(ri_s[i], w[(long)i * Lq], acc);
    }
    if (j < RCOLS) part[((long)b * RSPLIT + s) * RCOLS + j] = acc;
}

__global__ __launch_bounds__(64) void router_finish(
    const float* __restrict__ part, const float* __restrict__ noise,
    const float* __restrict__ br1, const float* __restrict__ Wr2,
    const float* __restrict__ br2, const float* __restrict__ bn,
    float* __restrict__ rw_out)
{
    __shared__ float rh[RH];
    __shared__ float ns[Lq];
    const int b = blockIdx.x, tid = threadIdx.x;

    for (int j = tid; j < RCOLS; j += 64) {
        float acc = 0.f;
        #pragma unroll
        for (int s = 0; s < RSPLIT; ++s)
            acc += part[((long)b * RSPLIT + s) * RCOLS + j];
        if (j < RH) {
            rh[j] = fmaxf(acc + br1[j], 0.f);
        } else {
            float v = acc + bn[j - RH];
            ns[j - RH] = (v > 20.f) ? v : log1pf(expf(v));
        }
    }
    __syncthreads();

    if (tid < Lq) {
        float acc = br2[tid];
        #pragma unroll 8
        for (int i = 0; i < RH; ++i) acc = fmaf(rh[i], Wr2[i * Lq + tid], acc);
        float z = (acc + noise[b * Lq + tid] * ns[tid]) * (1.f / TEMPER);
        float learned = 1.f / (1.f + expf(-z));
        rw_out[b * Lq + tid] = ALPHA * learned + (1.f - ALPHA) / (float)Lq;
    }
}

// ---------------------------------------------------------------------------
// fused = sum_l pooled*rw ; LayerNorm ; classifier (unchanged)
// ---------------------------------------------------------------------------
__device__ __forceinline__ float blockSum256(float v, volatile float* red)
{
    const int lane = threadIdx.x & 63, wave = threadIdx.x >> 6;
    #pragma unroll
    for (int off = 32; off; off >>= 1) v += __shfl_down(v, off);
    __syncthreads();
    if (lane == 0) red[wave] = v;
    __syncthreads();
    return red[0] + red[1] + red[2] + red[3];
}

__global__ __launch_bounds__(256) void fuse_classify(
    const float* __restrict__ pooled, const float* __restrict__ rw,
    const float* __restrict__ ln_g, const float* __restrict__ ln_b,
    const float* __restrict__ Wc1, const float* __restrict__ bc1,
    const float* __restrict__ Wc2, const float* __restrict__ bc2,
    float* __restrict__ fusedn_out, float* __restrict__ logits_out)
{
    __shared__ float rw_s[Lq];
    __shared__ float fn[Eq];
    __shared__ float red[4];

    const int b = blockIdx.x, tid = threadIdx.x;
    if (tid < Lq) rw_s[tid] = rw[b * Lq + tid];
    __syncthreads();

    const float* pb = pooled + (long)b * RIN;
    float f0 = 0.f, f1 = 0.f;
    #pragma unroll
    for (int l = 0; l < Lq; ++l) {
        f0 = fmaf(pb[l * Eq + tid],       rw_s[l], f0);
        f1 = fmaf(pb[l * Eq + tid + 256], rw_s[l], f1);
    }

    const float mean = blockSum256(f0 + f1, red) * (1.f / Eq);
    const float d0 = f0 - mean, d1 = f1 - mean;
    const float var = blockSum256(d0 * d0 + d1 * d1, red) * (1.f / Eq);
    const float rstd = rsqrtf(var + 1e-5f);

    const float n0v = d0 * rstd * ln_g[tid]       + ln_b[tid];
    const float n1v = d1 * rstd * ln_g[tid + 256] + ln_b[tid + 256];
    fn[tid] = n0v;
    fn[tid + 256] = n1v;
    fusedn_out[(long)b * Eq + tid]       = n0v;
    fusedn_out[(long)b * Eq + tid + 256] = n1v;
    __syncthreads();

    float acc = bc1[tid];
    #pragma unroll 8
    for (int f = 0; f < Eq; ++f) acc = fmaf(fn[f], Wc1[(long)f * 256 + tid], acc);
    const float c = fmaxf(acc, 0.f);

    const float t0 = blockSum256(c * Wc2[tid * 2 + 0], red);
    const float t1 = blockSum256(c * Wc2[tid * 2 + 1], red);
    if (tid == 0) {
        logits_out[b * 2 + 0] = t0 + bc2[0];
        logits_out[b * 2 + 1] = t1 + bc2[1];
    }
}

// ---------------------------------------------------------------------------
extern "C" void kernel_launch(void* const* d_in, const int* in_sizes, int n_in,
                              void* d_out, int out_size, void* d_ws, size_t ws_size,
                              hipStream_t stream)
{
    const float* h     = (const float*)d_in[0];
    const float* noise = (const float*)d_in[1];
    const float* We1   = (const float*)d_in[2];
    const float* be1   = (const float*)d_in[3];
    const float* We2   = (const float*)d_in[4];
    const float* be2   = (const float*)d_in[5];
    const float* wa    = (const float*)d_in[6];
    const float* ba    = (const float*)d_in[7];
    const float* Wr1   = (const float*)d_in[8];
    const float* br1   = (const float*)d_in[9];
    const float* Wr2   = (const float*)d_in[10];
    const float* br2   = (const float*)d_in[11];
    const float* Wn    = (const float*)d_in[12];
    const float* bn    = (const float*)d_in[13];
    const float* ln_g  = (const float*)d_in[14];
    const float* ln_b  = (const float*)d_in[15];
    const float* Wc1   = (const float*)d_in[16];
    const float* bc1   = (const float*)d_in[17];
    const float* Wc2   = (const float*)d_in[18];
    const float* bc2   = (const float*)d_in[19];

    float* out = (float*)d_out;
    // output layout: logits[16*2] | rw[16*24] | fused_n[16*512] | pooled[16*24*512]
    float* logits_out = out;
    float* rw_out     = out + 32;
    float* fusedn_out = out + 416;
    float* pooled_out = out + 8608;

    // workspace layout (bytes):
    //   h16  @ 0          : 157,286,400 halves (314,572,800 B) — x2 aliases this
    //   x1   @ 314572800  :  78,643,200 halves (157,286,400 B)
    //   w1t  @ 471859200  :  12,582,912 halves ( 25,165,824 B)
    //   w2t  @ 497025024  :   6,291,456 halves ( 12,582,912 B)
    //   part @ 509607936  :  16*8*152 floats
    char* ws = (char*)d_ws;
    _Float16* h16 = (_Float16*)ws;
    _Float16* x1  = (_Float16*)(ws + 314572800);
    _Float16* w1t = (_Float16*)(ws + 471859200);
    _Float16* w2t = (_Float16*)(ws + 497025024);
    float*    part= (float*)   (ws + 509607936);
    _Float16* x2  = h16;   // h16 dead after gemm1; reuse for x2

    // converts
    f32_to_f16<<<2048, 256, 0, stream>>>(h, h16, 157286400L / 4);
    transpose_to_f16<<<dim3(16, 32, Lq), 256, 0, stream>>>(We1, w1t, Dq, Eq);
    transpose_to_f16<<<dim3(16, 16, Lq), 256, 0, stream>>>(We2, w2t, Eq, Eq);

    // Stage 1: x1 = relu(h @ We1 + be1)   [fp16 MFMA]
    gemm_f16<<<dim3(4, 50, Lq), 256, 0, stream>>>(h16, w1t, be1, x1, Dq, 1);
    // Stage 2: x2 = x1 @ We2 + be2        [fp16 MFMA]
    gemm_f16<<<dim3(4, 50, Lq), 256, 0, stream>>>(x1, w2t, be2, x2, Eq, 0);

    // softmax-pool -> pooled (fp32, straight into d_out)
    softmax_pool_f16<<<dim3(Lq, Bq), 256, 0, stream>>>(x2, wa, ba, pooled_out);
    // router
    router_partial<<<dim3(Bq, RSPLIT), 192, 0, stream>>>(pooled_out, Wr1, Wn, part);
    router_finish<<<Bq, 64, 0, stream>>>(part, noise, br1, Wr2, br2, bn, rw_out);
    // fuse + LN + classifier
    fuse_classify<<<Bq, 256, 0, stream>>>(pooled_out, rw_out, ln_g, ln_b,
                                          Wc1, bc1, Wc2, bc2,
                                          fusedn_out, logits_out);
}